// Round 1
// baseline (412.237 us; speedup 1.0000x reference)
//
#include <hip/hip_runtime.h>
#include <hip/hip_bf16.h>

typedef short v8s __attribute__((ext_vector_type(8)));
typedef float v4f __attribute__((ext_vector_type(4)));

#define DD 128        // feature dim
#define KTOT 64       // output channels
#define RANK 16
#define KPB 8         // k-values per block (k-split = 8)
#define STRIPS_PER_RB 128   // 16-row strips per row-block (2048 rows)

// pack bf16(a) (lo) | bf16(b) (hi), round-toward-zero (1 v_perm_b32)
__device__ __forceinline__ unsigned int pk_bf16_trunc(float a, float b) {
  return __builtin_amdgcn_perm(__builtin_bit_cast(unsigned int, b),
                               __builtin_bit_cast(unsigned int, a),
                               0x07060302u);
}

// round-to-nearest-even bf16 (used only for one-time weight conversion)
__device__ __forceinline__ unsigned short bf16_rne(float x) {
  unsigned int u = __builtin_bit_cast(unsigned int, x);
  u += 0x7FFFu + ((u >> 16) & 1u);
  return (unsigned short)(u >> 16);
}

// Grid: 512 blocks = 8 k-groups x 64 row-blocks, XCD-swizzled.
// Block: 256 threads = 4 waves. LDS: exactly 64 KB -> 2 blocks/CU.
__global__ __launch_bounds__(256, 2)
void antisym_bilinear_kernel(const float* __restrict__ x1,
                             const float* __restrict__ x2,
                             const float* __restrict__ Wl,
                             const float* __restrict__ P,
                             const float* __restrict__ Q,
                             float* __restrict__ out) {
  // B-operand layout: [rr(8)][dblk(16)][col(16)][j(8)] bf16, col = (r&1)*8 + klocal
  __shared__ __align__(16) unsigned short Plds[16384];
  __shared__ __align__(16) unsigned short Qlds[16384];

  const int b   = blockIdx.x;
  const int xcd = b & 7;        // assumed XCD round-robin on blockIdx%8
  const int jj  = b >> 3;
  const int kg  = jj & 7;       // k-group: channels kg*8 .. kg*8+7
  const int rb  = xcd * 8 + (jj >> 3);  // all 8 kg of a row-range on one XCD

  const int tid  = threadIdx.x;
  const int lane = tid & 63;
  const int wave = tid >> 6;    // 0..3
  const int q    = lane >> 4;   // quad 0..3
  const int c    = lane & 15;   // MFMA m / n index

  // ---- one-time: stage this block's P/Q k-slice into LDS (bf16, B-frag layout)
  {
    const float* Pg = P + kg * (KPB * DD * RANK);
    const float* Qg = Q + kg * (KPB * DD * RANK);
    for (int f = tid; f < KPB * DD * RANK; f += 256) {
      int r  = f & 15;            // P layout [k][d][r], r innermost
      int d  = (f >> 4) & 127;
      int kl = f >> 11;
      int idx = (((r >> 1) * 16 + (d >> 3)) * 16 + ((r & 1) * 8 + kl)) * 8 + (d & 7);
      Plds[idx] = bf16_rne(Pg[f]);
      Qlds[idx] = bf16_rne(Qg[f]);
    }
  }

  // ---- one-time: W_lin B-fragments in registers; cols 8..15 = 0
  v8s Wf[4];
  {
    v8s wz = {0, 0, 0, 0, 0, 0, 0, 0};
    Wf[0] = wz; Wf[1] = wz; Wf[2] = wz; Wf[3] = wz;
    if (c < 8) {
      const float* wrow = Wl + (kg * 8 + c) * DD;
#pragma unroll
      for (int kk = 0; kk < 4; ++kk) {
        int d0 = kk * 32 + q * 8;
        float4 w0 = *(const float4*)(wrow + d0);
        float4 w1 = *(const float4*)(wrow + d0 + 4);
        union { v8s v; unsigned short h[8]; } t;
        t.h[0] = bf16_rne(w0.x); t.h[1] = bf16_rne(w0.y);
        t.h[2] = bf16_rne(w0.z); t.h[3] = bf16_rne(w0.w);
        t.h[4] = bf16_rne(w1.x); t.h[5] = bf16_rne(w1.y);
        t.h[6] = bf16_rne(w1.z); t.h[7] = bf16_rne(w1.w);
        Wf[kk] = t.v;
      }
    }
  }
  __syncthreads();   // only barrier in the kernel

  // ---- main loop: 8 groups x (4 strips of 16 rows) per wave
  for (int g = 0; g < 8; ++g) {
    const int strip0 = rb * STRIPS_PER_RB + g * 16 + wave * 4;

    // A-fragments for Z = x1-x2 and S = x1+x2, built straight from global
    v8s Zf[4][4], Sf[4][4];
#pragma unroll
    for (int t = 0; t < 4; ++t) {
      const int row = (strip0 + t) * 16 + c;       // A: m = lane&15
      const float4* p1 = (const float4*)(x1 + (long)row * DD);
      const float4* p2 = (const float4*)(x2 + (long)row * DD);
#pragma unroll
      for (int kk = 0; kk < 4; ++kk) {
        const int i0 = kk * 8 + q * 2;             // d0 = kk*32 + q*8
        float4 a0 = p1[i0], a1 = p1[i0 + 1];
        float4 b0 = p2[i0], b1 = p2[i0 + 1];
        union { v8s v; unsigned int u[4]; } z, s;
        z.u[0] = pk_bf16_trunc(a0.x - b0.x, a0.y - b0.y);
        z.u[1] = pk_bf16_trunc(a0.z - b0.z, a0.w - b0.w);
        z.u[2] = pk_bf16_trunc(a1.x - b1.x, a1.y - b1.y);
        z.u[3] = pk_bf16_trunc(a1.z - b1.z, a1.w - b1.w);
        s.u[0] = pk_bf16_trunc(a0.x + b0.x, a0.y + b0.y);
        s.u[1] = pk_bf16_trunc(a0.z + b0.z, a0.w + b0.w);
        s.u[2] = pk_bf16_trunc(a1.x + b1.x, a1.y + b1.y);
        s.u[3] = pk_bf16_trunc(a1.z + b1.z, a1.w + b1.w);
        Zf[t][kk] = z.v;
        Sf[t][kk] = s.v;
      }
    }

    v4f acc[4];
#pragma unroll
    for (int t = 0; t < 4; ++t) acc[t] = (v4f){0.f, 0.f, 0.f, 0.f};

    // r-pairs: cols 0..7 accumulate even r for k=0..7, cols 8..15 odd r
#pragma unroll
    for (int rr = 0; rr < 8; ++rr) {
      v8s Pf[4], Qf[4];
#pragma unroll
      for (int kk = 0; kk < 4; ++kk) {
        const int off = ((rr * 16 + (kk * 4 + q)) * 16 + c) * 8;
        Pf[kk] = *(const v8s*)(Plds + off);   // ds_read_b128, bank-balanced
        Qf[kk] = *(const v8s*)(Qlds + off);
      }
#pragma unroll
      for (int t = 0; t < 4; ++t) {
        v4f ap = (v4f){0.f, 0.f, 0.f, 0.f};
        v4f aq = (v4f){0.f, 0.f, 0.f, 0.f};
#pragma unroll
        for (int kk = 0; kk < 4; ++kk) {
          ap = __builtin_amdgcn_mfma_f32_16x16x32_bf16(Zf[t][kk], Pf[kk], ap, 0, 0, 0);
          aq = __builtin_amdgcn_mfma_f32_16x16x32_bf16(Sf[t][kk], Qf[kk], aq, 0, 0, 0);
        }
        acc[t] += ap * aq;   // elementwise: matching (row, k, r) pairs
      }
    }

    // linear term: lands in cols 0..7 (W cols 8..15 are zero)
#pragma unroll
    for (int t = 0; t < 4; ++t) {
#pragma unroll
      for (int kk = 0; kk < 4; ++kk)
        acc[t] = __builtin_amdgcn_mfma_f32_16x16x32_bf16(Zf[t][kk], Wf[kk], acc[t], 0, 0, 0);
    }

    // epilogue: fold odd-r half (cols 8..15) onto cols 0..7, store
#pragma unroll
    for (int t = 0; t < 4; ++t) {
      float v0 = acc[t][0], v1 = acc[t][1], v2 = acc[t][2], v3 = acc[t][3];
      v0 += __shfl_xor(v0, 8, 64);
      v1 += __shfl_xor(v1, 8, 64);
      v2 += __shfl_xor(v2, 8, 64);
      v3 += __shfl_xor(v3, 8, 64);
      const int row0 = (strip0 + t) * 16 + q * 4;  // C: row = quad*4 + reg
      const int cc = c & 7;
      float* op = out + (long)row0 * KTOT + kg * 8 + cc;
      if (c < 8) { op[0 * KTOT] = v0; op[1 * KTOT] = v1; }
      else       { op[2 * KTOT] = v2; op[3 * KTOT] = v3; }
    }
  }
}

extern "C" void kernel_launch(void* const* d_in, const int* in_sizes, int n_in,
                              void* d_out, int out_size, void* d_ws, size_t ws_size,
                              hipStream_t stream) {
  (void)in_sizes; (void)n_in; (void)d_ws; (void)ws_size; (void)out_size;
  const float* x1 = (const float*)d_in[0];
  const float* x2 = (const float*)d_in[1];
  const float* Wl = (const float*)d_in[2];
  const float* P  = (const float*)d_in[3];
  const float* Q  = (const float*)d_in[4];
  float* out = (float*)d_out;
  hipLaunchKernelGGL(antisym_bilinear_kernel, dim3(512), dim3(256), 0, stream,
                     x1, x2, Wl, P, Q, out);
}

// Round 2
// 216.624 us; speedup vs baseline: 1.9030x; 1.9030x over previous
//
#include <hip/hip_runtime.h>
#include <hip/hip_bf16.h>

typedef short v8s __attribute__((ext_vector_type(8)));
typedef float v4f __attribute__((ext_vector_type(4)));

#define DD 128
#define KTOT 64
#define RANK 16

// ws layout (shorts): P~ [0, 131072) | Q~ [131072, 262144) | W~ [262144, 278528)
// P~/Q~ fragment index: (((kg*8+rr)*4+kk)*64 + lane)*8 + j
//   lane=(q*16+c): k=kg*8+(c&7), r=2*rr+(c>>3), d=(kk*4+q)*8+j
// W~ fragment index: ((kg*4+kk)*64 + lane)*8 + j  (c>=8 lanes are zero)
#define QOFF 131072
#define WOFF 262144

__device__ __forceinline__ unsigned int pk_bf16_trunc(float a, float b) {
  return __builtin_amdgcn_perm(__builtin_bit_cast(unsigned int, b),
                               __builtin_bit_cast(unsigned int, a),
                               0x07060302u);
}

__device__ __forceinline__ unsigned short bf16_rne(float x) {
  unsigned int u = __builtin_bit_cast(unsigned int, x);
  u += 0x7FFFu + ((u >> 16) & 1u);
  return (unsigned short)(u >> 16);
}

// ---------------- pre-pass: swizzle weights into B-fragment layout ----------
__global__ __launch_bounds__(256)
void swizzle_weights_kernel(const float* __restrict__ Wl,
                            const float* __restrict__ P,
                            const float* __restrict__ Q,
                            unsigned short* __restrict__ ws) {
  const int tid = blockIdx.x * 256 + threadIdx.x;
  if (tid < 16384) {
    // P/Q fragments
    const int kg   = tid >> 11;
    const int rr   = (tid >> 8) & 7;
    const int kk   = (tid >> 6) & 3;
    const int lane = tid & 63;
    const int q = lane >> 4, c = lane & 15;
    const int k = kg * 8 + (c & 7);
    const int r = rr * 2 + (c >> 3);
    const int dbase = (kk * 4 + q) * 8;
    const float* Pg = P + ((long)k * DD) * RANK + r;   // P[k][d][r]
    const float* Qg = Q + ((long)k * DD) * RANK + r;
    union { v8s v; unsigned short h[8]; } po, qo;
#pragma unroll
    for (int j = 0; j < 8; ++j) {
      po.h[j] = bf16_rne(Pg[(long)(dbase + j) * RANK]);
      qo.h[j] = bf16_rne(Qg[(long)(dbase + j) * RANK]);
    }
    *(v8s*)(ws + (long)tid * 8)        = po.v;
    *(v8s*)(ws + QOFF + (long)tid * 8) = qo.v;
  } else if (tid < 16384 + 2048) {
    const int t2   = tid - 16384;
    const int kg   = t2 >> 8;
    const int kk   = (t2 >> 6) & 3;
    const int lane = t2 & 63;
    const int q = lane >> 4, c = lane & 15;
    union { v8s v; unsigned short h[8]; } wo;
#pragma unroll
    for (int j = 0; j < 8; ++j) wo.h[j] = 0;
    if (c < 8) {
      const float* wrow = Wl + (long)(kg * 8 + c) * DD + (kk * 4 + q) * 8;
#pragma unroll
      for (int j = 0; j < 8; ++j) wo.h[j] = bf16_rne(wrow[j]);
    }
    *(v8s*)(ws + WOFF + (long)t2 * 8) = wo.v;
  }
}

// ---------------- main kernel: 512 blocks x 256 rows, all 64 k per block ----
__global__ __launch_bounds__(256, 2)
void antisym_bilinear_kernel(const float* __restrict__ x1,
                             const float* __restrict__ x2,
                             const unsigned short* __restrict__ wsw,
                             float* __restrict__ out) {
  const int b    = blockIdx.x;      // 512 blocks, 256 rows each
  const int tid  = threadIdx.x;
  const int lane = tid & 63;
  const int wave = tid >> 6;        // 0..3
  const int q    = lane >> 4;
  const int c    = lane & 15;

  const int strip0 = b * 16 + wave * 4;   // 16-row strips; 4 per wave

  // ---- A-fragments (persistent): Z = x1-x2, S = x1+x2, built from global f32
  v8s Zf[4][4], Sf[4][4];
#pragma unroll
  for (int t = 0; t < 4; ++t) {
    const int row = (strip0 + t) * 16 + c;       // A: m = lane&15
    const float4* p1 = (const float4*)(x1 + (long)row * DD);
    const float4* p2 = (const float4*)(x2 + (long)row * DD);
#pragma unroll
    for (int kk = 0; kk < 4; ++kk) {
      const int i0 = kk * 8 + q * 2;             // d0 = kk*32 + q*8
      float4 a0 = p1[i0], a1 = p1[i0 + 1];
      float4 b0 = p2[i0], b1 = p2[i0 + 1];
      union { v8s v; unsigned int u[4]; } z, s;
      z.u[0] = pk_bf16_trunc(a0.x - b0.x, a0.y - b0.y);
      z.u[1] = pk_bf16_trunc(a0.z - b0.z, a0.w - b0.w);
      z.u[2] = pk_bf16_trunc(a1.x - b1.x, a1.y - b1.y);
      z.u[3] = pk_bf16_trunc(a1.z - b1.z, a1.w - b1.w);
      s.u[0] = pk_bf16_trunc(a0.x + b0.x, a0.y + b0.y);
      s.u[1] = pk_bf16_trunc(a0.z + b0.z, a0.w + b0.w);
      s.u[2] = pk_bf16_trunc(a1.x + b1.x, a1.y + b1.y);
      s.u[3] = pk_bf16_trunc(a1.z + b1.z, a1.w + b1.w);
      Zf[t][kk] = z.v;
      Sf[t][kk] = s.v;
    }
  }

  // ---- k-group loop: B-fragments straight from L2-resident pre-swizzled ws
  for (int kg = 0; kg < 8; ++kg) {
    // linear-term W fragments for this kg (issued early, used at the end)
    v8s Wf[4];
#pragma unroll
    for (int kk = 0; kk < 4; ++kk)
      Wf[kk] = *(const v8s*)(wsw + WOFF + (((long)(kg * 4 + kk) * 64 + lane) * 8));

    v4f acc[4];
#pragma unroll
    for (int t = 0; t < 4; ++t) acc[t] = (v4f){0.f, 0.f, 0.f, 0.f};

#pragma unroll
    for (int rr = 0; rr < 8; ++rr) {
      v8s Pf[4], Qf[4];
#pragma unroll
      for (int kk = 0; kk < 4; ++kk) {
        const long off = (((long)((kg * 8 + rr) * 4 + kk) * 64 + lane)) * 8;
        Pf[kk] = *(const v8s*)(wsw + off);          // coalesced 16B/lane
        Qf[kk] = *(const v8s*)(wsw + QOFF + off);
      }
#pragma unroll
      for (int t = 0; t < 4; ++t) {
        v4f ap = (v4f){0.f, 0.f, 0.f, 0.f};
        v4f aq = (v4f){0.f, 0.f, 0.f, 0.f};
#pragma unroll
        for (int kk = 0; kk < 4; ++kk) {
          ap = __builtin_amdgcn_mfma_f32_16x16x32_bf16(Zf[t][kk], Pf[kk], ap, 0, 0, 0);
          aq = __builtin_amdgcn_mfma_f32_16x16x32_bf16(Sf[t][kk], Qf[kk], aq, 0, 0, 0);
        }
        acc[t] += ap * aq;   // matching (row,k,r) pairs: pure VALU, no shuffles
      }
    }

    // linear term (W cols 8..15 are zero -> lands only in cols 0..7)
#pragma unroll
    for (int t = 0; t < 4; ++t) {
#pragma unroll
      for (int kk = 0; kk < 4; ++kk)
        acc[t] = __builtin_amdgcn_mfma_f32_16x16x32_bf16(Zf[t][kk], Wf[kk], acc[t], 0, 0, 0);
    }

    // epilogue: fold odd-r half (cols 8..15) onto cols 0..7, store 8 floats/row
#pragma unroll
    for (int t = 0; t < 4; ++t) {
      float v0 = acc[t][0], v1 = acc[t][1], v2 = acc[t][2], v3 = acc[t][3];
      v0 += __shfl_xor(v0, 8, 64);
      v1 += __shfl_xor(v1, 8, 64);
      v2 += __shfl_xor(v2, 8, 64);
      v3 += __shfl_xor(v3, 8, 64);
      const int row0 = (strip0 + t) * 16 + q * 4;  // C: row = quad*4 + reg
      const int cc = c & 7;
      float* op = out + (long)row0 * KTOT + kg * 8 + cc;
      if (c < 8) { op[0 * KTOT] = v0; op[1 * KTOT] = v1; }
      else       { op[2 * KTOT] = v2; op[3 * KTOT] = v3; }
    }
  }
}

extern "C" void kernel_launch(void* const* d_in, const int* in_sizes, int n_in,
                              void* d_out, int out_size, void* d_ws, size_t ws_size,
                              hipStream_t stream) {
  (void)in_sizes; (void)n_in; (void)ws_size; (void)out_size;
  const float* x1 = (const float*)d_in[0];
  const float* x2 = (const float*)d_in[1];
  const float* Wl = (const float*)d_in[2];
  const float* P  = (const float*)d_in[3];
  const float* Q  = (const float*)d_in[4];
  float* out = (float*)d_out;
  unsigned short* ws = (unsigned short*)d_ws;   // needs 544 KB

  hipLaunchKernelGGL(swizzle_weights_kernel, dim3(72), dim3(256), 0, stream,
                     Wl, P, Q, ws);
  hipLaunchKernelGGL(antisym_bilinear_kernel, dim3(512), dim3(256), 0, stream,
                     x1, x2, ws, out);
}